// Round 5
// baseline (471.990 us; speedup 1.0000x reference)
//
#include <hip/hip_runtime.h>
#include <stdint.h>

typedef _Float16 f16;
typedef _Float16 f16x4 __attribute__((ext_vector_type(4)));
typedef _Float16 f16x8 __attribute__((ext_vector_type(8)));
typedef float f32x4 __attribute__((ext_vector_type(4)));

#define NB 8
#define NN 4096
#define CC 768
#define SCALE_F 0.10206207261596577f  // 96^-0.5

// async global->LDS, 16B per lane; LDS dest = wave-uniform base + lane*16
#define GLDS16(gp, lp)                                                       \
  __builtin_amdgcn_global_load_lds(                                          \
      (__attribute__((address_space(1))) void*)(gp),                         \
      (__attribute__((address_space(3))) void*)(lp), 16, 0, 0)

// ---------------------------------------------------------------------------
// Kernel A: fp32 -> fp16 convert + transpose, 128n x 64c tiles.
//   x1t[b][c][n] = x1[b][n][c]; x2t[b][d][n] = x2[b][n][d]; x2b = f16(x2)
// Transposed output rows are 128 n = 256B segments, stored as 4x b128.
// ---------------------------------------------------------------------------
__global__ __launch_bounds__(256) void k_convert(
    const float* __restrict__ x1, const float* __restrict__ x2,
    f16* __restrict__ x1t, f16* __restrict__ x2t, f16* __restrict__ x2b) {
  __shared__ float tile[128][65];
  const int which = blockIdx.z >> 3;  // 0: x1, 1: x2
  const int b = blockIdx.z & 7;
  const int n0 = blockIdx.x << 7;   // 128-wide in n
  const int c0 = blockIdx.y << 6;   // 64-wide in c
  const float* src = (which ? x2 : x1) + (size_t)b * NN * CC;
  f16* dt = (which ? x2t : x1t) + (size_t)b * CC * NN;
  const int t = threadIdx.x;
  const int rowi = t >> 4;          // 0..15
  const int col4 = (t & 15) << 2;   // 0,4,..,60
#pragma unroll
  for (int it = 0; it < 8; ++it) {
    const int r = it * 16 + rowi;
    const float4 v =
        *reinterpret_cast<const float4*>(&src[(size_t)(n0 + r) * CC + c0 + col4]);
    tile[r][col4 + 0] = v.x;
    tile[r][col4 + 1] = v.y;
    tile[r][col4 + 2] = v.z;
    tile[r][col4 + 3] = v.w;
    if (which) {
      f16x4 o = {(f16)v.x, (f16)v.y, (f16)v.z, (f16)v.w};
      *reinterpret_cast<f16x4*>(
          &x2b[(size_t)b * NN * CC + (size_t)(n0 + r) * CC + c0 + col4]) = o;
    }
  }
  __syncthreads();
  const int c = t >> 2;             // 0..63 (output row within tile)
  const int ng = t & 3;             // n-group: 32 n-values each
  f16x8 o[4];
#pragma unroll
  for (int q = 0; q < 4; ++q)
#pragma unroll
    for (int j = 0; j < 8; ++j) o[q][j] = (f16)tile[ng * 32 + q * 8 + j][c];
  f16* op = &dt[(size_t)(c0 + c) * NN + n0 + ng * 32];
#pragma unroll
  for (int q = 0; q < 4; ++q)
    *reinterpret_cast<f16x8*>(op + q * 8) = o[q];
}

// ---------------------------------------------------------------------------
// Kernel B/D: bt-GEMM: C[m][n] (+)= sum_k A[m][k]*B[n][k]
// 128x128 tile, BK=32, 4 waves each 64x64 (4x4 of 16x16x32 MFMA).
// 4-stage LDS pipeline, prefetch distance 2, raw s_barrier + manual
// s_waitcnt vmcnt(8) (never a full drain): AITER-style K-loop.
//   iter it: [vmcnt(8); s_barrier]  -> all waves' stage(it) visible
//            ds_read buf[it&3]; MFMA
//            [lgkmcnt(0); s_barrier] -> all waves' reads landed
//            issue stage(it+3)       -> buffer last read at iter it-1: free
// 1-D grid + XCD-locality swizzle (assumes hw xcd = blockIdx.x % 8).
// ---------------------------------------------------------------------------
template <bool ATOMIC, int SWZ>
__global__ __launch_bounds__(256) void k_gemm_bt(
    const f16* __restrict__ A, const f16* __restrict__ B,
    float* __restrict__ C, int klen, int lda, int ldb, int ldc,
    size_t sA, size_t sB, size_t sC) {
  __shared__ __align__(16) f16 As[4][128 * 32];
  __shared__ __align__(16) f16 Bs[4][128 * 32];

  const int lin = blockIdx.x;
  const int xcd = lin & 7;
  const int slot = lin >> 3;
  int bx, by, b, ks;
  if (SWZ == 1) {
    b = xcd;                 // one batch per XCD
    ks = slot / 36;          // 4 sequential K-split phases
    const int item = slot % 36;
    bx = item % 6;
    by = item / 6;
  } else {
    b = xcd;                 // one batch per XCD
    ks = 0;
    bx = slot / 6;           // B n-chunk index (streamed)
    by = slot % 6;           // 6 consecutive tiles share the B chunk
  }

  const f16* Ap = A + (size_t)b * sA + (size_t)by * 128 * lda + (size_t)ks * klen;
  const f16* Bp = B + (size_t)b * sB + (size_t)bx * 128 * ldb + (size_t)ks * klen;
  float* Cp = C + (size_t)b * sC + (size_t)by * 128 * ldc + bx * 128;

  const int tid = threadIdx.x;
  const int wave = tid >> 6;
  const int lane = tid & 63;
  const int wr = wave >> 1;  // wave row (0/1) -> 64-row half
  const int wc = wave & 1;   // wave col (0/1) -> 64-col half

  // staging: wave w loads A rows [32w,32w+32) and B rows [32w,32w+32)
  const f16* ga0 = Ap + (size_t)(wave * 32 + (lane >> 2)) * lda + (lane & 3) * 8;
  const f16* ga1 = ga0 + (size_t)16 * lda;
  const f16* gb0 = Bp + (size_t)(wave * 32 + (lane >> 2)) * ldb + (lane & 3) * 8;
  const f16* gb1 = gb0 + (size_t)16 * ldb;
  const int lofs0 = wave * 32 * 32;       // wave-uniform LDS offsets
  const int lofs1 = lofs0 + 16 * 32;

  // fragment read offsets: lane holds row (lane&15), k = (lane>>4)*8 .. +7
  const int raofs = (wr * 64 + (lane & 15)) * 32 + (lane >> 4) * 8;
  const int rbofs = (wc * 64 + (lane & 15)) * 32 + (lane >> 4) * 8;

  f32x4 acc[4][4] = {};

  const int nit = klen >> 5;  // 32 (GEMM1) or 24 (GEMM2); must be >= 3

#define STAGE(s)                                                              \
  do {                                                                        \
    const int _s4 = (s) & 3;                                                  \
    const size_t _ko = (size_t)(s) * 32;                                      \
    GLDS16(ga0 + _ko, &As[_s4][lofs0]);                                       \
    GLDS16(ga1 + _ko, &As[_s4][lofs1]);                                       \
    GLDS16(gb0 + _ko, &Bs[_s4][lofs0]);                                       \
    GLDS16(gb1 + _ko, &Bs[_s4][lofs1]);                                       \
  } while (0)

  STAGE(0);
  STAGE(1);
  STAGE(2);

  for (int it = 0; it < nit; ++it) {
    // own stage(it) is 3rd-newest: <=8 outstanding => stage(it) complete.
    // barrier => every wave's stage(it) complete (each waited before arriving).
    asm volatile("s_waitcnt vmcnt(8)\n\ts_barrier" ::: "memory");
    const f16* ra = &As[it & 3][raofs];
    const f16* rb = &Bs[it & 3][rbofs];
    f16x8 af[4], bfv[4];
#pragma unroll
    for (int i = 0; i < 4; ++i)
      af[i] = *reinterpret_cast<const f16x8*>(ra + i * 16 * 32);
#pragma unroll
    for (int j = 0; j < 4; ++j)
      bfv[j] = *reinterpret_cast<const f16x8*>(rb + j * 16 * 32);
#pragma unroll
    for (int i = 0; i < 4; ++i)
#pragma unroll
      for (int j = 0; j < 4; ++j)
        acc[i][j] = __builtin_amdgcn_mfma_f32_16x16x32_f16(af[i], bfv[j],
                                                           acc[i][j], 0, 0, 0);
    // all own ds_reads landed; barrier => all waves done reading buf[it&3].
    asm volatile("s_waitcnt lgkmcnt(0)\n\ts_barrier" ::: "memory");
    if (it + 3 < nit) STAGE(it + 3);
  }
#undef STAGE

  // C/D layout (verified m89/m91, dtype-independent): col=lane&15, row=(lane>>4)*4+reg
  const int col = lane & 15;
  const int rq = (lane >> 4) * 4;
#pragma unroll
  for (int i = 0; i < 4; ++i) {
    const int r0 = wr * 64 + i * 16 + rq;
#pragma unroll
    for (int j = 0; j < 4; ++j) {
      const int cidx = wc * 64 + j * 16 + col;
#pragma unroll
      for (int r = 0; r < 4; ++r) {
        const float v = acc[i][j][r];
        if (ATOMIC)
          atomicAdd(&Cp[(size_t)(r0 + r) * ldc + cidx], v);
        else
          Cp[(size_t)(r0 + r) * ldc + cidx] = v;
      }
    }
  }
}

// ---------------------------------------------------------------------------
// Kernel C: row softmax over 768 logits (SCALE applied here), fp32 -> fp16.
// ---------------------------------------------------------------------------
__global__ __launch_bounds__(256) void k_softmax(const float* __restrict__ S,
                                                 f16* __restrict__ P) {
  const int row = blockIdx.x * 4 + (threadIdx.x >> 6);
  const int lane = threadIdx.x & 63;
  const float* s = S + (size_t)row * CC;
  float v[12];
#pragma unroll
  for (int j = 0; j < 3; ++j) {
    const float4 t = *reinterpret_cast<const float4*>(&s[j * 256 + lane * 4]);
    v[j * 4 + 0] = t.x * SCALE_F;
    v[j * 4 + 1] = t.y * SCALE_F;
    v[j * 4 + 2] = t.z * SCALE_F;
    v[j * 4 + 3] = t.w * SCALE_F;
  }
  float m = v[0];
#pragma unroll
  for (int j = 1; j < 12; ++j) m = fmaxf(m, v[j]);
#pragma unroll
  for (int off = 32; off >= 1; off >>= 1) m = fmaxf(m, __shfl_xor(m, off, 64));
  float sum = 0.f;
#pragma unroll
  for (int j = 0; j < 12; ++j) {
    v[j] = __expf(v[j] - m);
    sum += v[j];
  }
#pragma unroll
  for (int off = 32; off >= 1; off >>= 1) sum += __shfl_xor(sum, off, 64);
  const float inv = 1.0f / sum;
  f16* p = P + (size_t)row * CC;
#pragma unroll
  for (int j = 0; j < 3; ++j) {
    f16x4 o = {(f16)(v[j * 4 + 0] * inv), (f16)(v[j * 4 + 1] * inv),
               (f16)(v[j * 4 + 2] * inv), (f16)(v[j * 4 + 3] * inv)};
    *reinterpret_cast<f16x4*>(&p[j * 256 + lane * 4]) = o;
  }
}

// ---------------------------------------------------------------------------
extern "C" void kernel_launch(void* const* d_in, const int* in_sizes, int n_in,
                              void* d_out, int out_size, void* d_ws,
                              size_t ws_size, hipStream_t stream) {
  const float* x1 = (const float*)d_in[0];
  const float* x2 = (const float*)d_in[1];
  float* out = (float*)d_out;

  const size_t elems = (size_t)NB * NN * CC;  // 25165824
  // x1t/x2t live in d_out (2 * f16 arrays == out fp32 bytes exactly);
  // GEMM2 overwrites out only after GEMM1 consumed them.
  f16* x1t = (f16*)d_out;
  f16* x2t = x1t + elems;
  char* ws = (char*)d_ws;
  f16* x2b = (f16*)ws;                                     // 50.3 MB
  float* S = (float*)(ws + elems * 2);                     // 18.9 MB
  f16* P = (f16*)(ws + elems * 2 + (size_t)NB * CC * CC * 4);  // 9.4 MB
  const size_t need =
      elems * 2 + (size_t)NB * CC * CC * 4 + (size_t)NB * CC * CC * 2;
  if (ws_size < need) return;  // cannot run without scratch

  // A) convert + transpose
  k_convert<<<dim3(NN / 128, CC / 64, 2 * NB), 256, 0, stream>>>(x1, x2, x1t,
                                                                 x2t, x2b);
  // B) S = x1t . x2t^T  (split-K x4, atomic accumulate; S pre-zeroed)
  hipMemsetAsync(S, 0, (size_t)NB * CC * CC * 4, stream);
  k_gemm_bt<true, 1><<<dim3(6 * 6 * NB * 4), 256, 0, stream>>>(
      x1t, x2t, S, NN / 4, NN, NN, CC, (size_t)CC * NN, (size_t)CC * NN,
      (size_t)CC * CC);
  // C) P = softmax(SCALE * S) as fp16
  k_softmax<<<dim3(NB * CC / 4), 256, 0, stream>>>(S, P);
  // D) out = P . x2b^T
  k_gemm_bt<false, 2><<<dim3(32 * 6 * NB), 256, 0, stream>>>(
      P, x2b, out, CC, CC, CC, NN, (size_t)CC * CC, (size_t)NN * CC,
      (size_t)CC * NN);
}